// Round 1
// baseline (1357.586 us; speedup 1.0000x reference)
//
#include <hip/hip_runtime.h>
#include <hip/hip_bf16.h>

// GCNDecoder: 2-layer GCN, N=100000 nodes, E=1600000 edges, 64 -> 128 -> 64, fp32.
// Inputs: x[100000,64] f32, edge_index[2,1600000] int32, W3[64,128], b3[128],
//         W4[128,64], b4[64]. Output: [100000,64] f32.
//
// Pipeline (all per call; ws/out are re-poisoned before every timed launch):
//   K0 init:    deg=1.0 (self loop), agg1[r][c]=b3[c], out[r][c]=b4[c]
//   K1 degree:  atomicAdd deg[dst[e]] += 1
//   K2 rsqrt:   deg -> dinv
//   K3 gemm1:   h1 = x @ W3                     (LDS-tiled, fp32 VALU)
//   K4 scatter: agg1[d] += h1[s]*dinv[s]*dinv[d]  (E+N edges, C=128, atomics)
//   K5 gemm2:   h2 = relu(agg1) @ W4            (relu applied on LDS staging;
//                                                b3 was folded into agg1 init)
//   K6 scatter: out[d] += h2[s]*dinv[s]*dinv[d]   (C=64; b4 folded into init)
// h2 reuses h1's buffer. Workspace: deg(0.4MB) + h1(51.2MB) + agg1(51.2MB).

constexpr int IN_C  = 64;
constexpr int HID_C = 128;
constexpr int OUT_C = 64;

__global__ __launch_bounds__(256) void init_kernel(
    float* __restrict__ deg, float* __restrict__ agg1, float* __restrict__ out,
    const float* __restrict__ b3, const float* __restrict__ b4, int n)
{
    int i = blockIdx.x * 256 + threadIdx.x;
    if (i < n * HID_C) agg1[i] = b3[i & (HID_C - 1)];
    if (i < n * OUT_C) out[i]  = b4[i & (OUT_C - 1)];
    if (i < n)         deg[i]  = 1.0f;   // self-loop
}

__global__ __launch_bounds__(256) void degree_kernel(
    const int* __restrict__ dst, float* __restrict__ deg, int E)
{
    int e = blockIdx.x * 256 + threadIdx.x;
    if (e < E) atomicAdd(&deg[dst[e]], 1.0f);
}

__global__ __launch_bounds__(256) void rsqrt_kernel(float* __restrict__ deg, int n)
{
    int i = blockIdx.x * 256 + threadIdx.x;
    if (i < n) deg[i] = rsqrtf(deg[i]);   // deg >= 1 always (self-loop)
}

// h1[r][c] = sum_k x[r][k] * W3[k][c].  32 rows/block, 256 threads:
// 32 col-threads x 4 cols, 8 row-threads x 4 rows. W3 (32KB) + x-tile in LDS.
__global__ __launch_bounds__(256) void gemm1_kernel(
    const float* __restrict__ x, const float* __restrict__ W,
    float* __restrict__ h, int n)
{
    __shared__ float Ws[IN_C * HID_C];       // [k][c], 32 KB
    __shared__ float xs[32][IN_C + 1];       // +1 pad: break k-broadcast bank alias
    for (int i = threadIdx.x; i < IN_C * HID_C; i += 256) Ws[i] = W[i];
    int r0 = blockIdx.x * 32;
    for (int i = threadIdx.x; i < 32 * IN_C; i += 256) {
        int rr = i >> 6, kk = i & 63;
        int r = r0 + rr;
        xs[rr][kk] = (r < n) ? x[(size_t)r * IN_C + kk] : 0.0f;
    }
    __syncthreads();
    const int ct = threadIdx.x & 31;   // 32 * 4 = 128 cols
    const int rt = threadIdx.x >> 5;   // 8 * 4 = 32 rows
    float acc[4][4] = {};
    const float4* Ws4 = (const float4*)Ws;
    for (int k = 0; k < IN_C; ++k) {
        float4 w = Ws4[k * (HID_C / 4) + ct];
        #pragma unroll
        for (int ry = 0; ry < 4; ++ry) {
            float xv = xs[rt * 4 + ry][k];
            acc[ry][0] += xv * w.x; acc[ry][1] += xv * w.y;
            acc[ry][2] += xv * w.z; acc[ry][3] += xv * w.w;
        }
    }
    #pragma unroll
    for (int ry = 0; ry < 4; ++ry) {
        int r = r0 + rt * 4 + ry;
        if (r < n) {
            float4* o = (float4*)&h[(size_t)r * HID_C + ct * 4];
            *o = make_float4(acc[ry][0], acc[ry][1], acc[ry][2], acc[ry][3]);
        }
    }
}

// h2[r][c] = sum_k relu(agg1[r][k]) * W4[k][c].  32 rows/block:
// 16 col-threads x 4 cols (=64), 16 row-threads x 2 rows.
__global__ __launch_bounds__(256) void gemm2_kernel(
    const float* __restrict__ a, const float* __restrict__ W,
    float* __restrict__ h, int n)
{
    __shared__ float Ws[HID_C * OUT_C];      // [k][c], 32 KB
    __shared__ float xs[32][HID_C + 1];      // 16.1 KB
    for (int i = threadIdx.x; i < HID_C * OUT_C; i += 256) Ws[i] = W[i];
    int r0 = blockIdx.x * 32;
    for (int i = threadIdx.x; i < 32 * HID_C; i += 256) {
        int rr = i >> 7, kk = i & 127;
        int r = r0 + rr;
        float v = (r < n) ? a[(size_t)r * HID_C + kk] : 0.0f;
        xs[rr][kk] = fmaxf(v, 0.0f);         // relu (b3 already folded in)
    }
    __syncthreads();
    const int ct = threadIdx.x & 15;   // 16 * 4 = 64 cols
    const int rt = threadIdx.x >> 4;   // 16 * 2 = 32 rows
    float acc[2][4] = {};
    const float4* Ws4 = (const float4*)Ws;
    for (int k = 0; k < HID_C; ++k) {
        float4 w = Ws4[k * (OUT_C / 4) + ct];
        #pragma unroll
        for (int ry = 0; ry < 2; ++ry) {
            float xv = xs[rt * 2 + ry][k];
            acc[ry][0] += xv * w.x; acc[ry][1] += xv * w.y;
            acc[ry][2] += xv * w.z; acc[ry][3] += xv * w.w;
        }
    }
    #pragma unroll
    for (int ry = 0; ry < 2; ++ry) {
        int r = r0 + rt * 2 + ry;
        if (r < n) {
            float4* o = (float4*)&h[(size_t)r * OUT_C + ct * 4];
            *o = make_float4(acc[ry][0], acc[ry][1], acc[ry][2], acc[ry][3]);
        }
    }
}

// One thread per (edge, channel); C consecutive threads cover one edge's
// feature row -> coalesced gather + coalesced atomic scatter.
// Edges [0,E) are real edges; [E, E+n) are self-loops.
template <int C>
__global__ __launch_bounds__(256) void scatter_kernel(
    const float* __restrict__ h, const int* __restrict__ src,
    const int* __restrict__ dst, const float* __restrict__ dinv,
    float* __restrict__ agg, int E, int n)
{
    unsigned t = blockIdx.x * 256u + threadIdx.x;
    unsigned e = t / C;
    unsigned c = t % C;
    if (e >= (unsigned)(E + n)) return;
    int s, d;
    if (e < (unsigned)E) { s = src[e]; d = dst[e]; }
    else                 { s = d = (int)(e - E); }
    float w = dinv[s] * dinv[d];
    float v = h[(size_t)s * C + c] * w;
    atomicAdd(&agg[(size_t)d * C + c], v);
}

extern "C" void kernel_launch(void* const* d_in, const int* in_sizes, int n_in,
                              void* d_out, int out_size, void* d_ws, size_t ws_size,
                              hipStream_t stream)
{
    const float* x  = (const float*)d_in[0];
    const int*   ei = (const int*)d_in[1];
    const float* W3 = (const float*)d_in[2];
    const float* b3 = (const float*)d_in[3];
    const float* W4 = (const float*)d_in[4];
    const float* b4 = (const float*)d_in[5];
    float* out = (float*)d_out;

    const int n = in_sizes[0] / IN_C;   // 100000
    const int E = in_sizes[1] / 2;      // 1600000
    const int* src = ei;
    const int* dst = ei + E;

    // Workspace layout (floats): deg[n] | h1[n*128] (reused as h2) | agg1[n*128]
    float* deg  = (float*)d_ws;
    float* h1   = deg + (((size_t)n + 255) & ~(size_t)255);
    float* agg1 = h1 + (size_t)n * HID_C;

    const int nblk_init = (n * HID_C + 255) / 256;
    init_kernel<<<nblk_init, 256, 0, stream>>>(deg, agg1, out, b3, b4, n);

    degree_kernel<<<(E + 255) / 256, 256, 0, stream>>>(dst, deg, E);
    rsqrt_kernel<<<(n + 255) / 256, 256, 0, stream>>>(deg, n);

    gemm1_kernel<<<(n + 31) / 32, 256, 0, stream>>>(x, W3, h1, n);

    {
        long long tot = (long long)(E + n) * HID_C;
        int nblk = (int)((tot + 255) / 256);
        scatter_kernel<HID_C><<<nblk, 256, 0, stream>>>(h1, src, dst, deg, agg1, E, n);
    }

    gemm2_kernel<<<(n + 31) / 32, 256, 0, stream>>>(agg1, W4, h1, n);

    {
        long long tot = (long long)(E + n) * OUT_C;
        int nblk = (int)((tot + 255) / 256);
        scatter_kernel<OUT_C><<<nblk, 256, 0, stream>>>(h1, src, dst, deg, out, E, n);
    }
}

// Round 2
// 556.256 us; speedup vs baseline: 2.4406x; 2.4406x over previous
//
#include <hip/hip_runtime.h>
#include <hip/hip_bf16.h>

// GCNDecoder: 2-layer GCN, N=100000, E=1600000, 64 -> 128 -> 64, fp32.
//
// R1 rewrite: (a) layer-1 aggregation moved BEFORE the GEMM (linearity:
// A@(x W3) = (A@x) W3), so both aggregations run at C=64; (b) fp32 atomic
// scatter replaced by a per-call dst-CSR (counting sort) + one-wave-per-node
// gather aggregation with register accumulation and a single coalesced store.
// R0 profile: scatter atomics wrote 850 MB to HBM (L2 thrash); CSR agg writes
// 26 MB and gathers are LLC-resident.
//
// Pipeline:
//   zero_cnt -> hist(dst) -> scan1/scan2/scan3 (row_start, cursor, dinv)
//   -> fill (sorted_src) -> agg(x -> agg_x) -> gemm1 (r = relu(agg_x W3 + b3))
//   -> gemm2 (t = r W4) -> agg(t -> out, +b4)

constexpr int IN_C  = 64;
constexpr int HID_C = 128;
constexpr int OUT_C = 64;

__global__ __launch_bounds__(256) void zero_cnt_kernel(int* __restrict__ cnt, int n)
{
    int i = blockIdx.x * 256 + threadIdx.x;
    if (i < n) cnt[i] = 0;
}

__global__ __launch_bounds__(256) void hist_kernel(
    const int* __restrict__ dst, int* __restrict__ cnt, int E)
{
    int e = blockIdx.x * 256 + threadIdx.x;
    if (e < E) atomicAdd(&cnt[dst[e]], 1);
}

// Block-local exclusive scan of cnt -> row_start; block totals -> partials.
__global__ __launch_bounds__(256) void scan1_kernel(
    const int* __restrict__ cnt, int* __restrict__ row_start,
    int* __restrict__ partials, int n)
{
    __shared__ int s[256];
    int i = blockIdx.x * 256 + threadIdx.x;
    int v = (i < n) ? cnt[i] : 0;
    s[threadIdx.x] = v;
    __syncthreads();
    for (int off = 1; off < 256; off <<= 1) {
        int t = (threadIdx.x >= off) ? s[threadIdx.x - off] : 0;
        __syncthreads();
        s[threadIdx.x] += t;
        __syncthreads();
    }
    if (i < n) row_start[i] = s[threadIdx.x] - v;   // exclusive within block
    if (threadIdx.x == 255) partials[blockIdx.x] = s[255];
}

// Single-block exclusive scan of partials (nb <= 512).
__global__ __launch_bounds__(512) void scan2_kernel(int* __restrict__ partials, int nb)
{
    __shared__ int s[512];
    int v = (threadIdx.x < nb) ? partials[threadIdx.x] : 0;
    s[threadIdx.x] = v;
    __syncthreads();
    for (int off = 1; off < 512; off <<= 1) {
        int t = (threadIdx.x >= off) ? s[threadIdx.x - off] : 0;
        __syncthreads();
        s[threadIdx.x] += t;
        __syncthreads();
    }
    if (threadIdx.x < nb) partials[threadIdx.x] = s[threadIdx.x] - v;  // exclusive
}

__global__ __launch_bounds__(256) void scan3_kernel(
    const int* __restrict__ cnt, int* __restrict__ row_start,
    const int* __restrict__ partials, int* __restrict__ cursor,
    float* __restrict__ dinv, int n, int E)
{
    int i = blockIdx.x * 256 + threadIdx.x;
    if (i < n) {
        int rs = row_start[i] + partials[i >> 8];
        row_start[i] = rs;
        cursor[i] = rs;
        dinv[i] = rsqrtf((float)cnt[i] + 1.0f);   // +1: self-loop
    }
    if (i == 0) row_start[n] = E;
}

__global__ __launch_bounds__(256) void fill_kernel(
    const int* __restrict__ src, const int* __restrict__ dst,
    int* __restrict__ cursor, int* __restrict__ sorted_src, int E)
{
    int e = blockIdx.x * 256 + threadIdx.x;
    if (e < E) {
        int pos = atomicAdd(&cursor[dst[e]], 1);
        sorted_src[pos] = src[e];
    }
}

// One wave per node, lane = channel (C=64). Self-loop folded in:
// out[d] = dinv[d] * (feat[d]*dinv[d] + sum_s feat[s]*dinv[s]) [+ bias]
template <bool ADD_BIAS>
__global__ __launch_bounds__(256) void agg_kernel(
    const float* __restrict__ feat, const int* __restrict__ row_start,
    const int* __restrict__ sorted_src, const float* __restrict__ dinv,
    const float* __restrict__ bias, float* __restrict__ outp, int n)
{
    int wv = threadIdx.x >> 6;
    int lane = threadIdx.x & 63;
    int d = blockIdx.x * 4 + wv;
    if (d >= n) return;                 // wave-uniform exit
    float di = dinv[d];
    float acc = feat[(size_t)d * 64 + lane] * di;
    int beg = row_start[d], end = row_start[d + 1];
    int i = beg;
    for (; i + 2 <= end; i += 2) {      // 2-way unroll for load ILP
        int s0 = sorted_src[i], s1 = sorted_src[i + 1];
        float w0 = dinv[s0], w1 = dinv[s1];
        float v0 = feat[(size_t)s0 * 64 + lane];
        float v1 = feat[(size_t)s1 * 64 + lane];
        acc += v0 * w0;
        acc += v1 * w1;
    }
    if (i < end) {
        int s0 = sorted_src[i];
        acc += feat[(size_t)s0 * 64 + lane] * dinv[s0];
    }
    acc *= di;
    if (ADD_BIAS) acc += bias[lane];
    outp[(size_t)d * 64 + lane] = acc;
}

// r[row][c] = relu(sum_k agg_x[row][k] * W3[k][c] + b3[c]).
__global__ __launch_bounds__(256) void gemm1_kernel(
    const float* __restrict__ x, const float* __restrict__ W,
    const float* __restrict__ b, float* __restrict__ h, int n)
{
    __shared__ float Ws[IN_C * HID_C];       // [k][c], 32 KB
    __shared__ float xs[32][IN_C + 1];
    for (int i = threadIdx.x; i < IN_C * HID_C; i += 256) Ws[i] = W[i];
    int r0 = blockIdx.x * 32;
    for (int i = threadIdx.x; i < 32 * IN_C; i += 256) {
        int rr = i >> 6, kk = i & 63;
        int r = r0 + rr;
        xs[rr][kk] = (r < n) ? x[(size_t)r * IN_C + kk] : 0.0f;
    }
    __syncthreads();
    const int ct = threadIdx.x & 31;   // 32 x 4 = 128 cols
    const int rt = threadIdx.x >> 5;   // 8 x 4  = 32 rows
    float acc[4][4] = {};
    const float4* Ws4 = (const float4*)Ws;
    for (int k = 0; k < IN_C; ++k) {
        float4 w = Ws4[k * (HID_C / 4) + ct];
        #pragma unroll
        for (int ry = 0; ry < 4; ++ry) {
            float xv = xs[rt * 4 + ry][k];
            acc[ry][0] += xv * w.x; acc[ry][1] += xv * w.y;
            acc[ry][2] += xv * w.z; acc[ry][3] += xv * w.w;
        }
    }
    float4 bv = ((const float4*)b)[ct];
    #pragma unroll
    for (int ry = 0; ry < 4; ++ry) {
        int r = r0 + rt * 4 + ry;
        if (r < n) {
            float4* o = (float4*)&h[(size_t)r * HID_C + ct * 4];
            *o = make_float4(fmaxf(acc[ry][0] + bv.x, 0.0f),
                             fmaxf(acc[ry][1] + bv.y, 0.0f),
                             fmaxf(acc[ry][2] + bv.z, 0.0f),
                             fmaxf(acc[ry][3] + bv.w, 0.0f));
        }
    }
}

// t[row][c] = sum_k r[row][k] * W4[k][c]   (no bias/relu here)
__global__ __launch_bounds__(256) void gemm2_kernel(
    const float* __restrict__ a, const float* __restrict__ W,
    float* __restrict__ h, int n)
{
    __shared__ float Ws[HID_C * OUT_C];      // [k][c], 32 KB
    __shared__ float xs[32][HID_C + 1];
    for (int i = threadIdx.x; i < HID_C * OUT_C; i += 256) Ws[i] = W[i];
    int r0 = blockIdx.x * 32;
    for (int i = threadIdx.x; i < 32 * HID_C; i += 256) {
        int rr = i >> 7, kk = i & 127;
        int r = r0 + rr;
        xs[rr][kk] = (r < n) ? a[(size_t)r * HID_C + kk] : 0.0f;
    }
    __syncthreads();
    const int ct = threadIdx.x & 15;   // 16 x 4 = 64 cols
    const int rt = threadIdx.x >> 4;   // 16 x 2 = 32 rows
    float acc[2][4] = {};
    const float4* Ws4 = (const float4*)Ws;
    for (int k = 0; k < HID_C; ++k) {
        float4 w = Ws4[k * (OUT_C / 4) + ct];
        #pragma unroll
        for (int ry = 0; ry < 2; ++ry) {
            float xv = xs[rt * 2 + ry][k];
            acc[ry][0] += xv * w.x; acc[ry][1] += xv * w.y;
            acc[ry][2] += xv * w.z; acc[ry][3] += xv * w.w;
        }
    }
    #pragma unroll
    for (int ry = 0; ry < 2; ++ry) {
        int r = r0 + rt * 2 + ry;
        if (r < n) {
            float4* o = (float4*)&h[(size_t)r * OUT_C + ct * 4];
            *o = make_float4(acc[ry][0], acc[ry][1], acc[ry][2], acc[ry][3]);
        }
    }
}

extern "C" void kernel_launch(void* const* d_in, const int* in_sizes, int n_in,
                              void* d_out, int out_size, void* d_ws, size_t ws_size,
                              hipStream_t stream)
{
    const float* x  = (const float*)d_in[0];
    const int*   ei = (const int*)d_in[1];
    const float* W3 = (const float*)d_in[2];
    const float* b3 = (const float*)d_in[3];
    const float* W4 = (const float*)d_in[4];
    const float* b4 = (const float*)d_in[5];
    float* out = (float*)d_out;

    const int n = in_sizes[0] / IN_C;   // 100000
    const int E = in_sizes[1] / 2;      // 1600000
    const int* src = ei;
    const int* dst = ei + E;

    const size_t n_pad = ((size_t)n + 256) & ~(size_t)255;  // room for row_start[n]

    // Workspace layout: cnt | row_start | cursor | partials(512) | dinv |
    //                   sorted_src | agg_x (reused as t) | r
    int*   cnt       = (int*)d_ws;
    int*   row_start = cnt + n_pad;
    int*   cursor    = row_start + n_pad;
    int*   partials  = cursor + n_pad;
    float* dinv      = (float*)(partials + 512);
    int*   ssrc      = (int*)(dinv + n_pad);
    float* agg_x     = (float*)(ssrc + (((size_t)E + 255) & ~(size_t)255));
    float* r         = agg_x + (size_t)n * IN_C;
    float* t         = agg_x;                      // dead after gemm1

    const int nb  = (n + 255) / 256;   // 391
    const int neb = (E + 255) / 256;

    zero_cnt_kernel<<<nb, 256, 0, stream>>>(cnt, n);
    hist_kernel<<<neb, 256, 0, stream>>>(dst, cnt, E);
    scan1_kernel<<<nb, 256, 0, stream>>>(cnt, row_start, partials, n);
    scan2_kernel<<<1, 512, 0, stream>>>(partials, nb);
    scan3_kernel<<<nb, 256, 0, stream>>>(cnt, row_start, partials, cursor, dinv, n, E);
    fill_kernel<<<neb, 256, 0, stream>>>(src, dst, cursor, ssrc, E);

    agg_kernel<false><<<(n + 3) / 4, 256, 0, stream>>>(
        x, row_start, ssrc, dinv, nullptr, agg_x, n);

    gemm1_kernel<<<(n + 31) / 32, 256, 0, stream>>>(agg_x, W3, b3, r, n);
    gemm2_kernel<<<(n + 31) / 32, 256, 0, stream>>>(r, W4, t, n);

    agg_kernel<true><<<(n + 3) / 4, 256, 0, stream>>>(
        t, row_start, ssrc, dinv, b4, out, n);
}

// Round 3
// 500.758 us; speedup vs baseline: 2.7111x; 1.1108x over previous
//
#include <hip/hip_runtime.h>
#include <hip/hip_bf16.h>

// GCNDecoder: 2-layer GCN, N=100000, E=1600000, 64 -> 128 -> 64, fp32.
//
// R1: layer-1 aggregation moved before GEMM (linearity), dst-CSR + gather agg.
// R2: fill_kernel rewritten XCD-partitioned. R1 profile showed fill wrote
//     105 MB HBM for a 6.4 MB payload (one 64B partial-line writeback per 4B
//     store, because all 8 non-coherent XCD L2s scatter into the same region).
//     Now blocks with blockIdx%8==p (round-robin XCD heuristic) scan the whole
//     edge list (int4) and fill only dst-partition p -> each sorted_src line
//     is written by one XCD, accumulates in its L2, single writeback.
//     Edge list (12.8 MB) is LLC-resident so the 8x re-read is cheap.
//
// Pipeline:
//   zero_cnt -> hist(dst) -> scan1/scan2/scan3 (row_start, cursor, dinv)
//   -> fill_part (sorted_src) -> agg(x -> agg_x) -> gemm1 (r = relu(..W3+b3))
//   -> gemm2 (t = r W4) -> agg(t -> out, +b4)

constexpr int IN_C  = 64;
constexpr int HID_C = 128;
constexpr int OUT_C = 64;
constexpr int NPART = 8;            // XCD count

__global__ __launch_bounds__(256) void zero_cnt_kernel(int* __restrict__ cnt, int n)
{
    int i = blockIdx.x * 256 + threadIdx.x;
    if (i < n) cnt[i] = 0;
}

__global__ __launch_bounds__(256) void hist_kernel(
    const int* __restrict__ dst, int* __restrict__ cnt, int E)
{
    int e = blockIdx.x * 256 + threadIdx.x;
    if (e < E) atomicAdd(&cnt[dst[e]], 1);
}

// Block-local exclusive scan of cnt -> row_start; block totals -> partials.
__global__ __launch_bounds__(256) void scan1_kernel(
    const int* __restrict__ cnt, int* __restrict__ row_start,
    int* __restrict__ partials, int n)
{
    __shared__ int s[256];
    int i = blockIdx.x * 256 + threadIdx.x;
    int v = (i < n) ? cnt[i] : 0;
    s[threadIdx.x] = v;
    __syncthreads();
    for (int off = 1; off < 256; off <<= 1) {
        int t = (threadIdx.x >= off) ? s[threadIdx.x - off] : 0;
        __syncthreads();
        s[threadIdx.x] += t;
        __syncthreads();
    }
    if (i < n) row_start[i] = s[threadIdx.x] - v;   // exclusive within block
    if (threadIdx.x == 255) partials[blockIdx.x] = s[255];
}

// Single-block exclusive scan of partials (nb <= 512).
__global__ __launch_bounds__(512) void scan2_kernel(int* __restrict__ partials, int nb)
{
    __shared__ int s[512];
    int v = (threadIdx.x < nb) ? partials[threadIdx.x] : 0;
    s[threadIdx.x] = v;
    __syncthreads();
    for (int off = 1; off < 512; off <<= 1) {
        int t = (threadIdx.x >= off) ? s[threadIdx.x - off] : 0;
        __syncthreads();
        s[threadIdx.x] += t;
        __syncthreads();
    }
    if (threadIdx.x < nb) partials[threadIdx.x] = s[threadIdx.x] - v;  // exclusive
}

__global__ __launch_bounds__(256) void scan3_kernel(
    const int* __restrict__ cnt, int* __restrict__ row_start,
    const int* __restrict__ partials, int* __restrict__ cursor,
    float* __restrict__ dinv, int n, int E)
{
    int i = blockIdx.x * 256 + threadIdx.x;
    if (i < n) {
        int rs = row_start[i] + partials[i >> 8];
        row_start[i] = rs;
        cursor[i] = rs;
        dinv[i] = rsqrtf((float)cnt[i] + 1.0f);   // +1: self-loop
    }
    if (i == 0) row_start[n] = E;
}

// XCD-partitioned fill: partition p = blockIdx%8 owns dst in
// [p*psz, (p+1)*psz). Each partition's 96 blocks scan the whole edge list
// (int4, coalesced, LLC-resident) and fill only their own dsts.
__global__ __launch_bounds__(256) void fill_part_kernel(
    const int* __restrict__ src, const int* __restrict__ dst,
    int* __restrict__ cursor, int* __restrict__ sorted_src,
    int E, int psz)
{
    const int p   = blockIdx.x & (NPART - 1);
    const int q   = blockIdx.x / NPART;          // block index within partition
    const int QB  = gridDim.x / NPART;           // blocks per partition
    const int lo  = p * psz;
    const int hi  = lo + psz;                    // exclusive
    const int4* src4 = (const int4*)src;
    const int4* dst4 = (const int4*)dst;
    const int E4 = E >> 2;
    const int stride = QB * 256;
    for (int i4 = q * 256 + threadIdx.x; i4 < E4; i4 += stride) {
        int4 d4 = dst4[i4];
        int4 s4 = src4[i4];
        if (d4.x >= lo && d4.x < hi) sorted_src[atomicAdd(&cursor[d4.x], 1)] = s4.x;
        if (d4.y >= lo && d4.y < hi) sorted_src[atomicAdd(&cursor[d4.y], 1)] = s4.y;
        if (d4.z >= lo && d4.z < hi) sorted_src[atomicAdd(&cursor[d4.z], 1)] = s4.z;
        if (d4.w >= lo && d4.w < hi) sorted_src[atomicAdd(&cursor[d4.w], 1)] = s4.w;
    }
}

// One wave per node, lane = channel (C=64). Self-loop folded in:
// out[d] = dinv[d] * (feat[d]*dinv[d] + sum_s feat[s]*dinv[s]) [+ bias]
template <bool ADD_BIAS>
__global__ __launch_bounds__(256) void agg_kernel(
    const float* __restrict__ feat, const int* __restrict__ row_start,
    const int* __restrict__ sorted_src, const float* __restrict__ dinv,
    const float* __restrict__ bias, float* __restrict__ outp, int n)
{
    int wv = threadIdx.x >> 6;
    int lane = threadIdx.x & 63;
    int d = blockIdx.x * 4 + wv;
    if (d >= n) return;                 // wave-uniform exit
    float di = dinv[d];
    float acc = feat[(size_t)d * 64 + lane] * di;
    int beg = row_start[d], end = row_start[d + 1];
    int i = beg;
    for (; i + 2 <= end; i += 2) {      // 2-way unroll for load ILP
        int s0 = sorted_src[i], s1 = sorted_src[i + 1];
        float w0 = dinv[s0], w1 = dinv[s1];
        float v0 = feat[(size_t)s0 * 64 + lane];
        float v1 = feat[(size_t)s1 * 64 + lane];
        acc += v0 * w0;
        acc += v1 * w1;
    }
    if (i < end) {
        int s0 = sorted_src[i];
        acc += feat[(size_t)s0 * 64 + lane] * dinv[s0];
    }
    acc *= di;
    if (ADD_BIAS) acc += bias[lane];
    outp[(size_t)d * 64 + lane] = acc;
}

// r[row][c] = relu(sum_k agg_x[row][k] * W3[k][c] + b3[c]).
__global__ __launch_bounds__(256) void gemm1_kernel(
    const float* __restrict__ x, const float* __restrict__ W,
    const float* __restrict__ b, float* __restrict__ h, int n)
{
    __shared__ float Ws[IN_C * HID_C];       // [k][c], 32 KB
    __shared__ float xs[32][IN_C + 1];
    for (int i = threadIdx.x; i < IN_C * HID_C; i += 256) Ws[i] = W[i];
    int r0 = blockIdx.x * 32;
    for (int i = threadIdx.x; i < 32 * IN_C; i += 256) {
        int rr = i >> 6, kk = i & 63;
        int r = r0 + rr;
        xs[rr][kk] = (r < n) ? x[(size_t)r * IN_C + kk] : 0.0f;
    }
    __syncthreads();
    const int ct = threadIdx.x & 31;   // 32 x 4 = 128 cols
    const int rt = threadIdx.x >> 5;   // 8 x 4  = 32 rows
    float acc[4][4] = {};
    const float4* Ws4 = (const float4*)Ws;
    for (int k = 0; k < IN_C; ++k) {
        float4 w = Ws4[k * (HID_C / 4) + ct];
        #pragma unroll
        for (int ry = 0; ry < 4; ++ry) {
            float xv = xs[rt * 4 + ry][k];
            acc[ry][0] += xv * w.x; acc[ry][1] += xv * w.y;
            acc[ry][2] += xv * w.z; acc[ry][3] += xv * w.w;
        }
    }
    float4 bv = ((const float4*)b)[ct];
    #pragma unroll
    for (int ry = 0; ry < 4; ++ry) {
        int r = r0 + rt * 4 + ry;
        if (r < n) {
            float4* o = (float4*)&h[(size_t)r * HID_C + ct * 4];
            *o = make_float4(fmaxf(acc[ry][0] + bv.x, 0.0f),
                             fmaxf(acc[ry][1] + bv.y, 0.0f),
                             fmaxf(acc[ry][2] + bv.z, 0.0f),
                             fmaxf(acc[ry][3] + bv.w, 0.0f));
        }
    }
}

// t[row][c] = sum_k r[row][k] * W4[k][c]   (no bias/relu here)
__global__ __launch_bounds__(256) void gemm2_kernel(
    const float* __restrict__ a, const float* __restrict__ W,
    float* __restrict__ h, int n)
{
    __shared__ float Ws[HID_C * OUT_C];      // [k][c], 32 KB
    __shared__ float xs[32][HID_C + 1];
    for (int i = threadIdx.x; i < HID_C * OUT_C; i += 256) Ws[i] = W[i];
    int r0 = blockIdx.x * 32;
    for (int i = threadIdx.x; i < 32 * HID_C; i += 256) {
        int rr = i >> 7, kk = i & 127;
        int r = r0 + rr;
        xs[rr][kk] = (r < n) ? a[(size_t)r * HID_C + kk] : 0.0f;
    }
    __syncthreads();
    const int ct = threadIdx.x & 15;   // 16 x 4 = 64 cols
    const int rt = threadIdx.x >> 4;   // 16 x 2 = 32 rows
    float acc[2][4] = {};
    const float4* Ws4 = (const float4*)Ws;
    for (int k = 0; k < HID_C; ++k) {
        float4 w = Ws4[k * (OUT_C / 4) + ct];
        #pragma unroll
        for (int ry = 0; ry < 2; ++ry) {
            float xv = xs[rt * 2 + ry][k];
            acc[ry][0] += xv * w.x; acc[ry][1] += xv * w.y;
            acc[ry][2] += xv * w.z; acc[ry][3] += xv * w.w;
        }
    }
    #pragma unroll
    for (int ry = 0; ry < 2; ++ry) {
        int r = r0 + rt * 2 + ry;
        if (r < n) {
            float4* o = (float4*)&h[(size_t)r * OUT_C + ct * 4];
            *o = make_float4(acc[ry][0], acc[ry][1], acc[ry][2], acc[ry][3]);
        }
    }
}

extern "C" void kernel_launch(void* const* d_in, const int* in_sizes, int n_in,
                              void* d_out, int out_size, void* d_ws, size_t ws_size,
                              hipStream_t stream)
{
    const float* x  = (const float*)d_in[0];
    const int*   ei = (const int*)d_in[1];
    const float* W3 = (const float*)d_in[2];
    const float* b3 = (const float*)d_in[3];
    const float* W4 = (const float*)d_in[4];
    const float* b4 = (const float*)d_in[5];
    float* out = (float*)d_out;

    const int n = in_sizes[0] / IN_C;   // 100000
    const int E = in_sizes[1] / 2;      // 1600000
    const int* src = ei;
    const int* dst = ei + E;

    const size_t n_pad = ((size_t)n + 256) & ~(size_t)255;  // room for row_start[n]

    // Workspace layout: cnt | row_start | cursor | partials(512) | dinv |
    //                   sorted_src | agg_x (reused as t) | r
    int*   cnt       = (int*)d_ws;
    int*   row_start = cnt + n_pad;
    int*   cursor    = row_start + n_pad;
    int*   partials  = cursor + n_pad;
    float* dinv      = (float*)(partials + 512);
    int*   ssrc      = (int*)(dinv + n_pad);
    float* agg_x     = (float*)(ssrc + (((size_t)E + 255) & ~(size_t)255));
    float* r         = agg_x + (size_t)n * IN_C;
    float* t         = agg_x;                      // dead after gemm1

    const int nb  = (n + 255) / 256;   // 391
    const int neb = (E + 255) / 256;

    zero_cnt_kernel<<<nb, 256, 0, stream>>>(cnt, n);
    hist_kernel<<<neb, 256, 0, stream>>>(dst, cnt, E);
    scan1_kernel<<<nb, 256, 0, stream>>>(cnt, row_start, partials, n);
    scan2_kernel<<<1, 512, 0, stream>>>(partials, nb);
    scan3_kernel<<<nb, 256, 0, stream>>>(cnt, row_start, partials, cursor, dinv, n, E);

    {
        // 8 partitions x 96 blocks; partition size covers n rounded up.
        const int psz = (n + NPART - 1) / NPART;           // 12500
        fill_part_kernel<<<NPART * 96, 256, 0, stream>>>(src, dst, cursor, ssrc, E, psz);
    }

    agg_kernel<false><<<(n + 3) / 4, 256, 0, stream>>>(
        x, row_start, ssrc, dinv, nullptr, agg_x, n);

    gemm1_kernel<<<(n + 31) / 32, 256, 0, stream>>>(agg_x, W3, b3, r, n);
    gemm2_kernel<<<(n + 31) / 32, 256, 0, stream>>>(r, W4, t, n);

    agg_kernel<true><<<(n + 3) / 4, 256, 0, stream>>>(
        t, row_start, ssrc, dinv, b4, out, n);
}

// Round 4
// 447.475 us; speedup vs baseline: 3.0339x; 1.1191x over previous
//
#include <hip/hip_runtime.h>
#include <hip/hip_bf16.h>

// GCNDecoder: 2-layer GCN, N=100000, E=1600000, 64 -> 128 -> 64, fp32.
//
// R1: agg-before-GEMM (linearity), dst-CSR + gather agg (no fp32 atomics).
// R2: XCD-partitioned fill (write-amplification fix: 105 MB -> ~7 MB).
// R3: bf16 gather features. R2 profile: agg FETCH=194 MB/pass vs ~176 MB
//     structural floor for fp32 (8 non-coherent L2s x ~22 MB touched) -> the
//     only lever is element size. Gathered features are bf16-RN (x converted
//     once; gemm2 stores t directly as bf16); dinv weights, accumulators and
//     GEMMs stay fp32. agg gathers 128 B/row via half-wave-per-edge layout.
//
// Pipeline:
//   cvt(x->xh bf16) -> zero_cnt -> hist(dst) -> scan1/2/3 -> fill_part
//   -> agg_bf16(xh -> agg_x) -> gemm1 (r = relu(agg_x W3 + b3))
//   -> gemm2 (t = r W4, stored bf16) -> agg_bf16(t -> out, +b4)

constexpr int IN_C  = 64;
constexpr int HID_C = 128;
constexpr int OUT_C = 64;
constexpr int NPART = 8;            // XCD count

__device__ __forceinline__ unsigned bf16_rn(float f) {
    unsigned u = __float_as_uint(f);
    return (u + 0x7FFFu + ((u >> 16) & 1u)) >> 16;   // round-to-nearest-even
}

// Pack 2 consecutive fp32 into one u32 of bf16 pairs (low word = even channel).
__global__ __launch_bounds__(256) void cvt_kernel(
    const float2* __restrict__ in, unsigned* __restrict__ outw, int nw)
{
    int i = blockIdx.x * 256 + threadIdx.x;
    if (i < nw) {
        float2 v = in[i];
        outw[i] = bf16_rn(v.x) | (bf16_rn(v.y) << 16);
    }
}

__global__ __launch_bounds__(256) void zero_cnt_kernel(int* __restrict__ cnt, int n)
{
    int i = blockIdx.x * 256 + threadIdx.x;
    if (i < n) cnt[i] = 0;
}

__global__ __launch_bounds__(256) void hist_kernel(
    const int* __restrict__ dst, int* __restrict__ cnt, int E)
{
    int e = blockIdx.x * 256 + threadIdx.x;
    if (e < E) atomicAdd(&cnt[dst[e]], 1);
}

__global__ __launch_bounds__(256) void scan1_kernel(
    const int* __restrict__ cnt, int* __restrict__ row_start,
    int* __restrict__ partials, int n)
{
    __shared__ int s[256];
    int i = blockIdx.x * 256 + threadIdx.x;
    int v = (i < n) ? cnt[i] : 0;
    s[threadIdx.x] = v;
    __syncthreads();
    for (int off = 1; off < 256; off <<= 1) {
        int t = (threadIdx.x >= off) ? s[threadIdx.x - off] : 0;
        __syncthreads();
        s[threadIdx.x] += t;
        __syncthreads();
    }
    if (i < n) row_start[i] = s[threadIdx.x] - v;
    if (threadIdx.x == 255) partials[blockIdx.x] = s[255];
}

__global__ __launch_bounds__(512) void scan2_kernel(int* __restrict__ partials, int nb)
{
    __shared__ int s[512];
    int v = (threadIdx.x < nb) ? partials[threadIdx.x] : 0;
    s[threadIdx.x] = v;
    __syncthreads();
    for (int off = 1; off < 512; off <<= 1) {
        int t = (threadIdx.x >= off) ? s[threadIdx.x - off] : 0;
        __syncthreads();
        s[threadIdx.x] += t;
        __syncthreads();
    }
    if (threadIdx.x < nb) partials[threadIdx.x] = s[threadIdx.x] - v;
}

__global__ __launch_bounds__(256) void scan3_kernel(
    const int* __restrict__ cnt, int* __restrict__ row_start,
    const int* __restrict__ partials, int* __restrict__ cursor,
    float* __restrict__ dinv, int n, int E)
{
    int i = blockIdx.x * 256 + threadIdx.x;
    if (i < n) {
        int rs = row_start[i] + partials[i >> 8];
        row_start[i] = rs;
        cursor[i] = rs;
        dinv[i] = rsqrtf((float)cnt[i] + 1.0f);   // +1: self-loop
    }
    if (i == 0) row_start[n] = E;
}

// XCD-partitioned fill (see R2 note above).
__global__ __launch_bounds__(256) void fill_part_kernel(
    const int* __restrict__ src, const int* __restrict__ dst,
    int* __restrict__ cursor, int* __restrict__ sorted_src,
    int E, int psz)
{
    const int p   = blockIdx.x & (NPART - 1);
    const int q   = blockIdx.x / NPART;
    const int QB  = gridDim.x / NPART;
    const int lo  = p * psz;
    const int hi  = lo + psz;
    const int4* src4 = (const int4*)src;
    const int4* dst4 = (const int4*)dst;
    const int E4 = E >> 2;                       // E divisible by 4 here
    const int stride = QB * 256;
    for (int i4 = q * 256 + threadIdx.x; i4 < E4; i4 += stride) {
        int4 d4 = dst4[i4];
        int4 s4 = src4[i4];
        if (d4.x >= lo && d4.x < hi) sorted_src[atomicAdd(&cursor[d4.x], 1)] = s4.x;
        if (d4.y >= lo && d4.y < hi) sorted_src[atomicAdd(&cursor[d4.y], 1)] = s4.y;
        if (d4.z >= lo && d4.z < hi) sorted_src[atomicAdd(&cursor[d4.z], 1)] = s4.z;
        if (d4.w >= lo && d4.w < hi) sorted_src[atomicAdd(&cursor[d4.w], 1)] = s4.w;
    }
}

// One wave per dst node. feat is packed bf16 (32 u32 words / row = 64 ch).
// Half-wave-per-edge: lanes [0,32) process edges beg,beg+2,..; lanes [32,64)
// process beg+1,beg+3,..; each half gathers a full 128 B row (32 x u32).
// Lane lc holds fp32 acc for channels (2lc, 2lc+1); halves combined by shfl.
// out[d] = dinv_d*(feat[d]*dinv_d + sum_s feat[s]*dinv_s) [+ bias], fp32.
template <bool ADD_BIAS>
__global__ __launch_bounds__(256) void agg_bf16_kernel(
    const unsigned* __restrict__ feat, const int* __restrict__ row_start,
    const int* __restrict__ sorted_src, const float* __restrict__ dinv,
    const float* __restrict__ bias, float* __restrict__ outp, int n)
{
    const int wv   = threadIdx.x >> 6;
    const int lane = threadIdx.x & 63;
    const int half = lane >> 5;
    const int lc   = lane & 31;
    const int d    = blockIdx.x * 4 + wv;
    if (d >= n) return;                 // wave-uniform exit
    const float di = dinv[d];
    float ax = 0.0f, ay = 0.0f;
    if (half == 0) {                    // self-loop term (once)
        unsigned u = feat[(size_t)d * 32 + lc];
        ax = __uint_as_float(u << 16) * di;
        ay = __uint_as_float(u & 0xFFFF0000u) * di;
    }
    const int beg = row_start[d], end = row_start[d + 1];
    int i = beg + half;
    for (; i + 2 < end; i += 4) {       // 2x unroll per half (4 edges/wave/iter)
        int s0 = sorted_src[i], s1 = sorted_src[i + 2];
        float w0 = dinv[s0], w1 = dinv[s1];
        unsigned u0 = feat[(size_t)s0 * 32 + lc];
        unsigned u1 = feat[(size_t)s1 * 32 + lc];
        ax += __uint_as_float(u0 << 16) * w0;
        ay += __uint_as_float(u0 & 0xFFFF0000u) * w0;
        ax += __uint_as_float(u1 << 16) * w1;
        ay += __uint_as_float(u1 & 0xFFFF0000u) * w1;
    }
    if (i < end) {
        int s0 = sorted_src[i];
        float w0 = dinv[s0];
        unsigned u0 = feat[(size_t)s0 * 32 + lc];
        ax += __uint_as_float(u0 << 16) * w0;
        ay += __uint_as_float(u0 & 0xFFFF0000u) * w0;
    }
    // combine halves (lanes >= 32 read wrapped values; only lanes < 32 store)
    float ox = ax + __shfl(ax, lane + 32);
    float oy = ay + __shfl(ay, lane + 32);
    if (half == 0) {
        float2 o;
        o.x = ox * di;
        o.y = oy * di;
        if (ADD_BIAS) {
            const float2 bv = ((const float2*)bias)[lc];
            o.x += bv.x; o.y += bv.y;
        }
        ((float2*)outp)[(size_t)d * 32 + lc] = o;
    }
}

// r[row][c] = relu(sum_k agg_x[row][k] * W3[k][c] + b3[c]).  fp32 in/out.
__global__ __launch_bounds__(256) void gemm1_kernel(
    const float* __restrict__ x, const float* __restrict__ W,
    const float* __restrict__ b, float* __restrict__ h, int n)
{
    __shared__ float Ws[IN_C * HID_C];       // [k][c], 32 KB
    __shared__ float xs[32][IN_C + 1];
    for (int i = threadIdx.x; i < IN_C * HID_C; i += 256) Ws[i] = W[i];
    int r0 = blockIdx.x * 32;
    for (int i = threadIdx.x; i < 32 * IN_C; i += 256) {
        int rr = i >> 6, kk = i & 63;
        int r = r0 + rr;
        xs[rr][kk] = (r < n) ? x[(size_t)r * IN_C + kk] : 0.0f;
    }
    __syncthreads();
    const int ct = threadIdx.x & 31;   // 32 x 4 = 128 cols
    const int rt = threadIdx.x >> 5;   // 8 x 4  = 32 rows
    float acc[4][4] = {};
    const float4* Ws4 = (const float4*)Ws;
    for (int k = 0; k < IN_C; ++k) {
        float4 w = Ws4[k * (HID_C / 4) + ct];
        #pragma unroll
        for (int ry = 0; ry < 4; ++ry) {
            float xv = xs[rt * 4 + ry][k];
            acc[ry][0] += xv * w.x; acc[ry][1] += xv * w.y;
            acc[ry][2] += xv * w.z; acc[ry][3] += xv * w.w;
        }
    }
    float4 bv = ((const float4*)b)[ct];
    #pragma unroll
    for (int ry = 0; ry < 4; ++ry) {
        int r = r0 + rt * 4 + ry;
        if (r < n) {
            float4* o = (float4*)&h[(size_t)r * HID_C + ct * 4];
            *o = make_float4(fmaxf(acc[ry][0] + bv.x, 0.0f),
                             fmaxf(acc[ry][1] + bv.y, 0.0f),
                             fmaxf(acc[ry][2] + bv.z, 0.0f),
                             fmaxf(acc[ry][3] + bv.w, 0.0f));
        }
    }
}

// t[row][c] = sum_k r[row][k] * W4[k][c], stored as packed bf16 (32 u32/row).
__global__ __launch_bounds__(256) void gemm2_kernel(
    const float* __restrict__ a, const float* __restrict__ W,
    unsigned* __restrict__ hb, int n)
{
    __shared__ float Ws[HID_C * OUT_C];      // [k][c], 32 KB
    __shared__ float xs[32][HID_C + 1];
    for (int i = threadIdx.x; i < HID_C * OUT_C; i += 256) Ws[i] = W[i];
    int r0 = blockIdx.x * 32;
    for (int i = threadIdx.x; i < 32 * HID_C; i += 256) {
        int rr = i >> 7, kk = i & 127;
        int r = r0 + rr;
        xs[rr][kk] = (r < n) ? a[(size_t)r * HID_C + kk] : 0.0f;
    }
    __syncthreads();
    const int ct = threadIdx.x & 15;   // 16 x 4 = 64 cols
    const int rt = threadIdx.x >> 4;   // 16 x 2 = 32 rows
    float acc[2][4] = {};
    const float4* Ws4 = (const float4*)Ws;
    for (int k = 0; k < HID_C; ++k) {
        float4 w = Ws4[k * (OUT_C / 4) + ct];
        #pragma unroll
        for (int ry = 0; ry < 2; ++ry) {
            float xv = xs[rt * 2 + ry][k];
            acc[ry][0] += xv * w.x; acc[ry][1] += xv * w.y;
            acc[ry][2] += xv * w.z; acc[ry][3] += xv * w.w;
        }
    }
    #pragma unroll
    for (int ry = 0; ry < 2; ++ry) {
        int r = r0 + rt * 2 + ry;
        if (r < n) {
            uint2 pw;
            pw.x = bf16_rn(acc[ry][0]) | (bf16_rn(acc[ry][1]) << 16);
            pw.y = bf16_rn(acc[ry][2]) | (bf16_rn(acc[ry][3]) << 16);
            *(uint2*)&hb[(size_t)r * 32 + ct * 2] = pw;
        }
    }
}

extern "C" void kernel_launch(void* const* d_in, const int* in_sizes, int n_in,
                              void* d_out, int out_size, void* d_ws, size_t ws_size,
                              hipStream_t stream)
{
    const float* x  = (const float*)d_in[0];
    const int*   ei = (const int*)d_in[1];
    const float* W3 = (const float*)d_in[2];
    const float* b3 = (const float*)d_in[3];
    const float* W4 = (const float*)d_in[4];
    const float* b4 = (const float*)d_in[5];
    float* out = (float*)d_out;

    const int n = in_sizes[0] / IN_C;   // 100000
    const int E = in_sizes[1] / 2;      // 1600000
    const int* src = ei;
    const int* dst = ei + E;

    const size_t n_pad = ((size_t)n + 256) & ~(size_t)255;  // room for row_start[n]

    // Workspace: cnt | row_start | cursor | partials(512) | dinv | ssrc |
    //            xh (n*32 u32, reused as t) | agg_x (n*64 f) | r (n*128 f)
    int*      cnt       = (int*)d_ws;
    int*      row_start = cnt + n_pad;
    int*      cursor    = row_start + n_pad;
    int*      partials  = cursor + n_pad;
    float*    dinv      = (float*)(partials + 512);
    int*      ssrc      = (int*)(dinv + n_pad);
    unsigned* xh        = (unsigned*)(ssrc + (((size_t)E + 255) & ~(size_t)255));
    float*    agg_x     = (float*)(xh + n_pad * 32);
    float*    r         = agg_x + (size_t)n * IN_C;
    unsigned* t         = xh;                      // xh dead after agg1

    const int nb  = (n + 255) / 256;   // 391
    const int neb = (E + 255) / 256;

    cvt_kernel<<<(n * (IN_C / 2) + 255) / 256, 256, 0, stream>>>(
        (const float2*)x, xh, n * (IN_C / 2));

    zero_cnt_kernel<<<nb, 256, 0, stream>>>(cnt, n);
    hist_kernel<<<neb, 256, 0, stream>>>(dst, cnt, E);
    scan1_kernel<<<nb, 256, 0, stream>>>(cnt, row_start, partials, n);
    scan2_kernel<<<1, 512, 0, stream>>>(partials, nb);
    scan3_kernel<<<nb, 256, 0, stream>>>(cnt, row_start, partials, cursor, dinv, n, E);

    {
        const int psz = (n + NPART - 1) / NPART;           // 12500
        fill_part_kernel<<<NPART * 96, 256, 0, stream>>>(src, dst, cursor, ssrc, E, psz);
    }

    agg_bf16_kernel<false><<<(n + 3) / 4, 256, 0, stream>>>(
        xh, row_start, ssrc, dinv, nullptr, agg_x, n);

    gemm1_kernel<<<(n + 31) / 32, 256, 0, stream>>>(agg_x, W3, b3, r, n);
    gemm2_kernel<<<(n + 31) / 32, 256, 0, stream>>>(r, W4, t, n);

    agg_bf16_kernel<true><<<(n + 3) / 4, 256, 0, stream>>>(
        t, row_start, ssrc, dinv, b4, out, n);
}